// Round 1
// baseline (164.175 us; speedup 1.0000x reference)
//
#include <hip/hip_runtime.h>
#include <math.h>

#define HW    64
#define CIN   64
#define COUT  64
#define BATCH 8
#define KK    9
#define NPIX  (BATCH*HW*HW)      // 32768

// ---------------------------------------------------------------------------
// Kernel: transpose weights w[o][c][ky][kx] -> wt[f][c][o]  (f = ky*3+kx)
// ---------------------------------------------------------------------------
__global__ void k_prep_w(const float* __restrict__ w, float* __restrict__ wt) {
    int t = blockIdx.x * 256 + threadIdx.x;          // 0 .. 36863
    if (t >= COUT * CIN * KK) return;
    int o = t & 63;
    int c = (t >> 6) & 63;
    int f = t >> 12;
    wt[t] = w[(o * CIN + c) * KK + f];               // wt[(f*64+c)*64+o]
}

// ---------------------------------------------------------------------------
// Kernel: transpose x NCHW -> NHWC  (xt[b][y][x][c])
// block = 64 threads (lane = c), grid = B*H
// ---------------------------------------------------------------------------
__global__ void k_transpose(const float* __restrict__ x, float* __restrict__ xt) {
    int lane = threadIdx.x;                          // channel
    int by   = blockIdx.x;                           // b*64 + y
    int b = by >> 6, y = by & 63;
    const float* src = x + ((size_t)(b * 64 + lane)) * (HW * HW) + y * HW;
    float* dst = xt + ((size_t)(b * 64 + y)) * (HW * 64) + lane;
    for (int x4 = 0; x4 < HW; x4 += 4) {
        float4 v = *(const float4*)(src + x4);
        dst[(x4 + 0) * 64] = v.x;
        dst[(x4 + 1) * 64] = v.y;
        dst[(x4 + 2) * 64] = v.z;
        dst[(x4 + 3) * 64] = v.w;
    }
}

// ---------------------------------------------------------------------------
// Kernel: fused offset+mask 3x3 conv (27 output channels), raw[ch][pixel]
// grid = (NPIX/256, 3): blockIdx.y selects channel group of 9
// ---------------------------------------------------------------------------
__global__ __launch_bounds__(256) void k_conv(
        const float* __restrict__ x,
        const float* __restrict__ w_off, const float* __restrict__ b_off,
        const float* __restrict__ w_mod, const float* __restrict__ b_mod,
        float* __restrict__ raw) {
    int t = blockIdx.x * 256 + threadIdx.x;          // pixel id 0..32767
    int g = blockIdx.y;                              // channel group 0..2
    int j = t & 63, i = (t >> 6) & 63, b = t >> 12;

    const float* wbase;
    const float* bias;
    int chbase = g * 9;
    if (g < 2) { wbase = w_off + (size_t)chbase * (CIN * KK); bias = b_off + chbase; }
    else       { wbase = w_mod;                               bias = b_mod; }

    float acc[9];
    #pragma unroll
    for (int ch = 0; ch < 9; ++ch) acc[ch] = bias[ch];

    const float* xb = x + (size_t)b * (CIN * HW * HW);
    for (int c = 0; c < CIN; ++c) {
        float xv[9];
        #pragma unroll
        for (int ky = 0; ky < 3; ++ky) {
            #pragma unroll
            for (int kx = 0; kx < 3; ++kx) {
                int y = i - 1 + ky, xx = j - 1 + kx;
                bool ok = ((unsigned)y < 64u) & ((unsigned)xx < 64u);
                xv[ky * 3 + kx] = ok ? xb[c * (HW * HW) + y * HW + xx] : 0.f;
            }
        }
        const float* wc = wbase + c * KK;            // uniform -> s_load
        #pragma unroll
        for (int ch = 0; ch < 9; ++ch) {
            const float* wk = wc + (size_t)ch * (CIN * KK);
            #pragma unroll
            for (int k = 0; k < 9; ++k) acc[ch] += xv[k] * wk[k];
        }
    }
    #pragma unroll
    for (int ch = 0; ch < 9; ++ch) raw[(size_t)(chbase + ch) * NPIX + t] = acc[ch];
}

// ---------------------------------------------------------------------------
// Kernel: per-(pixel, tap) bilinear metadata
//   metaW[pix*9+f] = 4 corner weights (validity-zeroed, pre-multiplied by mask)
//   metaO[pix*9+f] = 4 clamped corner offsets into xt's (y*64+x)*64 plane
// ---------------------------------------------------------------------------
__global__ void k_meta(const float* __restrict__ raw,
                       float4* __restrict__ metaW, int4* __restrict__ metaO) {
    int t = blockIdx.x * 256 + threadIdx.x;          // 0 .. NPIX*9-1
    if (t >= NPIX * KK) return;
    int pix = t / 9;
    int f   = t - pix * 9;
    int j = pix & 63, i = (pix >> 6) & 63;

    float dy = raw[(size_t)(2 * f)     * NPIX + pix];
    float dx = raw[(size_t)(2 * f + 1) * NPIX + pix];
    float mv = raw[(size_t)(18 + f)    * NPIX + pix];
    float m  = 1.f / (1.f + expf(-mv));              // sigmoid(mask)

    float ys = (float)(i - 1 + f / 3) + dy;
    float xs = (float)(j - 1 + f % 3) + dx;
    float y0f = floorf(ys), x0f = floorf(xs);
    int   y0  = (int)y0f,   x0  = (int)x0f;
    float fy = ys - y0f, fx = xs - x0f;

    bool vy0 = (unsigned)y0       < 64u, vy1 = (unsigned)(y0 + 1) < 64u;
    bool vx0 = (unsigned)x0       < 64u, vx1 = (unsigned)(x0 + 1) < 64u;
    float w00 = (vy0 & vx0) ? (1.f - fy) * (1.f - fx) * m : 0.f;
    float w01 = (vy0 & vx1) ? (1.f - fy) * fx         * m : 0.f;
    float w10 = (vy1 & vx0) ? fy         * (1.f - fx) * m : 0.f;
    float w11 = (vy1 & vx1) ? fy         * fx         * m : 0.f;

    int y0c = min(max(y0, 0), 63),     y1c = min(max(y0 + 1, 0), 63);
    int x0c = min(max(x0, 0), 63),     x1c = min(max(x0 + 1, 0), 63);

    metaW[t] = make_float4(w00, w01, w10, w11);
    metaO[t] = make_int4((y0c * 64 + x0c) * 64, (y0c * 64 + x1c) * 64,
                         (y1c * 64 + x0c) * 64, (y1c * 64 + x1c) * 64);
}

// ---------------------------------------------------------------------------
// Main deformable conv kernel.
// Block = 256 threads (4 waves), handles 64 pixels (one output row) x 64 Cout.
// Per tap f:
//   gather phase: wave wv samples pixels [wv*16, wv*16+16), lane = channel,
//                 coalesced NHWC corner loads, result -> s_lds[p][c] (pad 65)
//   GEMM phase:   lane = pixel, wave owns output channels [wv*16, wv*16+16);
//                 weights via wave-uniform address -> SGPR broadcast
// ---------------------------------------------------------------------------
__global__ __launch_bounds__(256) void k_main(
        const float* __restrict__ xt,
        const float4* __restrict__ metaW, const int4* __restrict__ metaO,
        const float* __restrict__ wt, const float* __restrict__ bias,
        float* __restrict__ out) {
    __shared__ float s_lds[64 * 65];

    int lane = threadIdx.x & 63;
    int wv   = __builtin_amdgcn_readfirstlane((int)(threadIdx.x >> 6));
    int blk  = blockIdx.x;                           // b*64 + i
    int b = blk >> 6, i = blk & 63;
    int pixBase = blk * 64;                          // row of 64 pixels, j = p
    const float* xb = xt + (size_t)b * (HW * HW * 64);
    int orange = wv * 16;

    float acc[16];
    #pragma unroll
    for (int oo = 0; oo < 16; ++oo) acc[oo] = 0.f;

    for (int f = 0; f < KK; ++f) {
        __syncthreads();                             // s_lds free to overwrite
        #pragma unroll
        for (int p16 = 0; p16 < 16; ++p16) {
            int p  = orange + p16;                   // wave's pixel
            int mi = (pixBase + p) * 9 + f;          // wave-uniform -> s_load
            float4 wts = metaW[mi];
            int4   off = metaO[mi];
            float v = wts.x * xb[off.x + lane]
                    + wts.y * xb[off.y + lane]
                    + wts.z * xb[off.z + lane]
                    + wts.w * xb[off.w + lane];
            s_lds[p * 65 + lane] = v;
        }
        __syncthreads();

        const float* wf = wt + f * (CIN * COUT) + orange;   // uniform
        for (int c = 0; c < CIN; ++c) {
            float s = s_lds[lane * 65 + c];          // (lane+c)%32 -> 2-way, free
            const float* wc = wf + c * 64;           // s_load_dwordx16
            #pragma unroll
            for (int oo = 0; oo < 16; ++oo)
                acc[oo] += s * wc[oo];
        }
    }

    #pragma unroll
    for (int oo = 0; oo < 16; ++oo) {
        int o = orange + oo;
        out[(((size_t)b * 64 + o) * 64 + i) * 64 + lane] = acc[oo] + bias[o];
    }
}

// ---------------------------------------------------------------------------
extern "C" void kernel_launch(void* const* d_in, const int* in_sizes, int n_in,
                              void* d_out, int out_size, void* d_ws, size_t ws_size,
                              hipStream_t stream) {
    const float* x     = (const float*)d_in[0];
    const float* w_off = (const float*)d_in[1];
    const float* b_off = (const float*)d_in[2];
    const float* w_mod = (const float*)d_in[3];
    const float* b_mod = (const float*)d_in[4];
    const float* w     = (const float*)d_in[5];
    const float* bias  = (const float*)d_in[6];
    float* out = (float*)d_out;

    char* ws = (char*)d_ws;
    float*  xt    = (float*)(ws);                    //  8,388,608 B
    float*  raw   = (float*)(ws + 8388608);          //  3,538,944 B
    float4* metaW = (float4*)(ws + 11927552);        //  4,718,592 B
    int4*   metaO = (int4*)(ws + 16646144);          //  4,718,592 B
    float*  wt    = (float*)(ws + 21364736);         //    147,456 B

    hipLaunchKernelGGL(k_prep_w,    dim3(144),      dim3(256), 0, stream, w, wt);
    hipLaunchKernelGGL(k_transpose, dim3(512),      dim3(64),  0, stream, x, xt);
    hipLaunchKernelGGL(k_conv,      dim3(128, 3),   dim3(256), 0, stream,
                       x, w_off, b_off, w_mod, b_mod, raw);
    hipLaunchKernelGGL(k_meta,      dim3(1152),     dim3(256), 0, stream,
                       raw, metaW, metaO);
    hipLaunchKernelGGL(k_main,      dim3(512),      dim3(256), 0, stream,
                       xt, metaW, metaO, wt, bias, out);
}

// Round 2
// 107.937 us; speedup vs baseline: 1.5210x; 1.5210x over previous
//
#include <hip/hip_runtime.h>
#include <math.h>

#define HW    64
#define CIN   64
#define COUT  64
#define BATCH 8
#define KK    9
#define NPIX  (BATCH*HW*HW)      // 32768

typedef __attribute__((ext_vector_type(8))) short bf16x8;
typedef __attribute__((ext_vector_type(4))) float f32x4;

static __device__ inline short f2bf(float f) {
    union { float f; unsigned u; } v; v.f = f;
    unsigned r = v.u + 0x7fff + ((v.u >> 16) & 1);   // RNE
    return (short)(r >> 16);
}

// ---------------------------------------------------------------------------
// Prep: wt2[f][o][c] bf16 (main weight), wc2[f][ch32][c] bf16 (off+mod, pad 32)
// ---------------------------------------------------------------------------
__global__ void k_prep(const float* __restrict__ w,
                       const float* __restrict__ w_off,
                       const float* __restrict__ w_mod,
                       short* __restrict__ wt2, short* __restrict__ wc2) {
    int t = blockIdx.x * 256 + threadIdx.x;
    if (t < 9 * 64 * 64) {
        int c = t & 63, o = (t >> 6) & 63, f = t >> 12;
        wt2[t] = f2bf(w[(o * 64 + c) * 9 + f]);
    }
    int u = t - 9 * 64 * 64;
    if (u >= 0 && u < 9 * 32 * 64) {
        int c = u & 63, ch = (u >> 6) & 31, f = u >> 11;
        float v = 0.f;
        if (ch < 18)      v = w_off[(ch * 64 + c) * 9 + f];
        else if (ch < 27) v = w_mod[((ch - 18) * 64 + c) * 9 + f];
        wc2[u] = f2bf(v);
    }
}

// ---------------------------------------------------------------------------
// Transpose x NCHW -> NHWC (xt[b][y][x][c]); block 64 (lane=c), grid B*H
// ---------------------------------------------------------------------------
__global__ void k_transpose(const float* __restrict__ x, float* __restrict__ xt) {
    int lane = threadIdx.x;
    int by   = blockIdx.x;
    int b = by >> 6, y = by & 63;
    const float* src = x + ((size_t)(b * 64 + lane)) * (HW * HW) + y * HW;
    float* dst = xt + ((size_t)(b * 64 + y)) * (HW * 64) + lane;
    for (int x4 = 0; x4 < HW; x4 += 4) {
        float4 v = *(const float4*)(src + x4);
        dst[(x4 + 0) * 64] = v.x;
        dst[(x4 + 1) * 64] = v.y;
        dst[(x4 + 2) * 64] = v.z;
        dst[(x4 + 3) * 64] = v.w;
    }
}

// ---------------------------------------------------------------------------
// Offset+mask 3x3 conv via MFMA. Block = 256 (4 waves) = one row (b,i),
// M=64 pixels, N=32 (27 real ch). Wave wv: m-frags {2*(wv&1),+1}, n-frag wv>>1.
// raw[ch][pix] output (ch-major, coalesced for k_meta).
// ---------------------------------------------------------------------------
__global__ __launch_bounds__(256) void k_conv(
        const float* __restrict__ xt, const short* __restrict__ wc2,
        const float* __restrict__ b_off, const float* __restrict__ b_mod,
        float* __restrict__ raw) {
    __shared__ __align__(16) char smem[9216];        // s_a[64][72]bf16 / s_out[32][65]f32
    short* s_a  = (short*)smem;
    float* s_out = (float*)smem;

    int lane = threadIdx.x & 63;
    int wv   = __builtin_amdgcn_readfirstlane((int)(threadIdx.x >> 6));
    int blk  = blockIdx.x;                           // b*64 + i
    int b = blk >> 6, i = blk & 63;
    const float* xb = xt + (size_t)b * (HW * HW * 64);

    int nbase = (wv >> 1) * 16;                      // channel base
    int mbase = (wv & 1) * 32;                       // pixel base of 2 m-frags

    bf16x8 bfrag[9][2];
    {
        int o = nbase + (lane & 15);
        int cb = (lane >> 4) * 8;
        #pragma unroll
        for (int f = 0; f < 9; ++f)
            #pragma unroll
            for (int kk = 0; kk < 2; ++kk)
                bfrag[f][kk] = *(const bf16x8*)(wc2 + (f * 32 + o) * 64 + kk * 32 + cb);
    }

    f32x4 acc[2];
    #pragma unroll
    for (int m = 0; m < 2; ++m) acc[m] = (f32x4){0.f, 0.f, 0.f, 0.f};

    for (int f = 0; f < 9; ++f) {
        int y = i + f / 3 - 1;
        int dx = f % 3 - 1;
        __syncthreads();
        #pragma unroll
        for (int p16 = 0; p16 < 16; ++p16) {
            int p  = wv * 16 + p16;                  // pixel (= x coord j)
            int xx = p + dx;
            bool ok = ((unsigned)y < 64u) & ((unsigned)xx < 64u);
            float v = ok ? xb[(y * 64 + xx) * 64 + lane] : 0.f;
            s_a[p * 72 + lane] = f2bf(v);
        }
        __syncthreads();
        int arow = lane & 15, acol = (lane >> 4) * 8;
        #pragma unroll
        for (int kk = 0; kk < 2; ++kk)
            #pragma unroll
            for (int mm = 0; mm < 2; ++mm) {
                bf16x8 afrag = *(const bf16x8*)(s_a + (mbase + mm * 16 + arow) * 72 + kk * 32 + acol);
                acc[mm] = __builtin_amdgcn_mfma_f32_16x16x32_bf16(afrag, bfrag[f][kk], acc[mm], 0, 0, 0);
            }
    }
    __syncthreads();
    {   // C frags -> s_out[ch][p]
        int ch = nbase + (lane & 15);
        int pr = (lane >> 4) * 4;
        #pragma unroll
        for (int mm = 0; mm < 2; ++mm)
            #pragma unroll
            for (int r = 0; r < 4; ++r)
                s_out[ch * 65 + mbase + mm * 16 + pr + r] = acc[mm][r];
    }
    __syncthreads();
    int pixBase = blk * 64;
    for (int ch = wv; ch < 27; ch += 4) {
        float bv = ch < 18 ? b_off[ch] : b_mod[ch - 18];
        raw[(size_t)ch * NPIX + pixBase + lane] = s_out[ch * 65 + lane] + bv;
    }
}

// ---------------------------------------------------------------------------
// Bilinear metadata, thread = pixel, meta layout [f][pix] (all coalesced).
// ---------------------------------------------------------------------------
__global__ __launch_bounds__(256) void k_meta(const float* __restrict__ raw,
                       float4* __restrict__ metaW, int4* __restrict__ metaO) {
    int pix = blockIdx.x * 256 + threadIdx.x;        // grid 128
    int j = pix & 63, i = (pix >> 6) & 63;
    #pragma unroll
    for (int f = 0; f < 9; ++f) {
        float dy = raw[(size_t)(2 * f)     * NPIX + pix];
        float dx = raw[(size_t)(2 * f + 1) * NPIX + pix];
        float mv = raw[(size_t)(18 + f)    * NPIX + pix];
        float m  = 1.f / (1.f + expf(-mv));

        float ys = (float)(i - 1 + f / 3) + dy;
        float xs = (float)(j - 1 + f % 3) + dx;
        float y0f = floorf(ys), x0f = floorf(xs);
        int   y0  = (int)y0f,   x0  = (int)x0f;
        float fy = ys - y0f, fx = xs - x0f;

        bool vy0 = (unsigned)y0       < 64u, vy1 = (unsigned)(y0 + 1) < 64u;
        bool vx0 = (unsigned)x0       < 64u, vx1 = (unsigned)(x0 + 1) < 64u;
        float w00 = (vy0 & vx0) ? (1.f - fy) * (1.f - fx) * m : 0.f;
        float w01 = (vy0 & vx1) ? (1.f - fy) * fx         * m : 0.f;
        float w10 = (vy1 & vx0) ? fy         * (1.f - fx) * m : 0.f;
        float w11 = (vy1 & vx1) ? fy         * fx         * m : 0.f;

        int y0c = min(max(y0, 0), 63), y1c = min(max(y0 + 1, 0), 63);
        int x0c = min(max(x0, 0), 63), x1c = min(max(x0 + 1, 0), 63);

        metaW[f * NPIX + pix] = make_float4(w00, w01, w10, w11);
        metaO[f * NPIX + pix] = make_int4((y0c * 64 + x0c) * 64, (y0c * 64 + x1c) * 64,
                                          (y1c * 64 + x0c) * 64, (y1c * 64 + x1c) * 64);
    }
}

// ---------------------------------------------------------------------------
// Main deformable conv: block 256 = one row (b,i), 64 pixels x 64 Cout.
// Per tap: gather -> LDS bf16 [64][72]; 2 k-steps x 4 m-frags MFMA.
// Wave wv owns outputs [wv*16, +16). B-frags preloaded (wt2 = B^T rows).
// ---------------------------------------------------------------------------
__global__ __launch_bounds__(256) void k_main(
        const float* __restrict__ xt,
        const float4* __restrict__ metaW, const int4* __restrict__ metaO,
        const short* __restrict__ wt2, const float* __restrict__ bias,
        float* __restrict__ out) {
    __shared__ __align__(16) char smem[16640];       // s_a[64][72]bf16 / s_out[64][65]f32
    short* s_a  = (short*)smem;
    float* s_out = (float*)smem;

    int lane = threadIdx.x & 63;
    int wv   = __builtin_amdgcn_readfirstlane((int)(threadIdx.x >> 6));
    int blk  = blockIdx.x;                           // b*64 + i
    int b = blk >> 6, i = blk & 63;
    int pixBase = blk * 64;
    const float* xb = xt + (size_t)b * (HW * HW * 64);
    int orange = wv * 16;

    bf16x8 bfrag[9][2];
    {
        int o = orange + (lane & 15);
        int cb = (lane >> 4) * 8;
        #pragma unroll
        for (int f = 0; f < 9; ++f)
            #pragma unroll
            for (int kk = 0; kk < 2; ++kk)
                bfrag[f][kk] = *(const bf16x8*)(wt2 + (f * 64 + o) * 64 + kk * 32 + cb);
    }

    f32x4 acc[4];
    #pragma unroll
    for (int m = 0; m < 4; ++m) acc[m] = (f32x4){0.f, 0.f, 0.f, 0.f};

    for (int f = 0; f < 9; ++f) {
        __syncthreads();
        #pragma unroll
        for (int p16 = 0; p16 < 16; ++p16) {
            int p  = orange + p16;
            int mi = f * NPIX + pixBase + p;         // wave-uniform -> s_load
            float4 wts = metaW[mi];
            int4   off = metaO[mi];
            float v = wts.x * xb[off.x + lane]
                    + wts.y * xb[off.y + lane]
                    + wts.z * xb[off.z + lane]
                    + wts.w * xb[off.w + lane];
            s_a[p * 72 + lane] = f2bf(v);
        }
        __syncthreads();
        int arow = lane & 15, acol = (lane >> 4) * 8;
        #pragma unroll
        for (int kk = 0; kk < 2; ++kk)
            #pragma unroll
            for (int m = 0; m < 4; ++m) {
                bf16x8 afrag = *(const bf16x8*)(s_a + (m * 16 + arow) * 72 + kk * 32 + acol);
                acc[m] = __builtin_amdgcn_mfma_f32_16x16x32_bf16(afrag, bfrag[f][kk], acc[m], 0, 0, 0);
            }
    }
    __syncthreads();
    {   // C frags -> s_out[p][o]
        int oc = lane & 15;
        int pr = (lane >> 4) * 4;
        #pragma unroll
        for (int m = 0; m < 4; ++m)
            #pragma unroll
            for (int r = 0; r < 4; ++r)
                s_out[(m * 16 + pr + r) * 65 + orange + oc] = acc[m][r];
    }
    __syncthreads();
    #pragma unroll
    for (int oo = 0; oo < 16; ++oo) {
        int o = orange + oo;
        out[(((size_t)b * 64 + o) * 64 + i) * 64 + lane] = s_out[lane * 65 + o] + bias[o];
    }
}

// ---------------------------------------------------------------------------
extern "C" void kernel_launch(void* const* d_in, const int* in_sizes, int n_in,
                              void* d_out, int out_size, void* d_ws, size_t ws_size,
                              hipStream_t stream) {
    const float* x     = (const float*)d_in[0];
    const float* w_off = (const float*)d_in[1];
    const float* b_off = (const float*)d_in[2];
    const float* w_mod = (const float*)d_in[3];
    const float* b_mod = (const float*)d_in[4];
    const float* w     = (const float*)d_in[5];
    const float* bias  = (const float*)d_in[6];
    float* out = (float*)d_out;

    char* ws = (char*)d_ws;
    float*  xt    = (float*)(ws);                    //  8,388,608 B
    float*  raw   = (float*)(ws + 8388608);          //  3,538,944 B
    float4* metaW = (float4*)(ws + 11927552);        //  4,718,592 B
    int4*   metaO = (int4*)(ws + 16646144);          //  4,718,592 B
    short*  wt2   = (short*)(ws + 21364736);         //     73,728 B
    short*  wc2   = (short*)(ws + 21438464);         //     36,864 B

    hipLaunchKernelGGL(k_prep,      dim3(216), dim3(256), 0, stream, w, w_off, w_mod, wt2, wc2);
    hipLaunchKernelGGL(k_transpose, dim3(512), dim3(64),  0, stream, x, xt);
    hipLaunchKernelGGL(k_conv,      dim3(512), dim3(256), 0, stream, xt, wc2, b_off, b_mod, raw);
    hipLaunchKernelGGL(k_meta,      dim3(128), dim3(256), 0, stream, raw, metaW, metaO);
    hipLaunchKernelGGL(k_main,      dim3(512), dim3(256), 0, stream,
                       xt, metaW, metaO, wt2, bias, out);
}

// Round 3
// 65.846 us; speedup vs baseline: 2.4933x; 1.6392x over previous
//
#include <hip/hip_runtime.h>
#include <math.h>

#define HW    64
#define CIN   64
#define COUT  64
#define BATCH 8
#define KK    9
#define NPIX  (BATCH*HW*HW)      // 32768

typedef __attribute__((ext_vector_type(8))) short bf16x8;
typedef __attribute__((ext_vector_type(8))) short short8v;
typedef __attribute__((ext_vector_type(4))) float f32x4;

static __device__ inline short f2bf(float f) {
    union { float f; unsigned u; } v; v.f = f;
    unsigned r = v.u + 0x7fff + ((v.u >> 16) & 1);   // RNE
    return (short)(r >> 16);
}
static __device__ inline float bf2f(short s) {
    union { unsigned u; float f; } v; v.u = ((unsigned)(unsigned short)s) << 16;
    return v.f;
}

// ---------------------------------------------------------------------------
// Prep: wt2[f][o][c] bf16 (main weight), wc2[f][ch32][c] bf16 (off+mod, pad 32)
// ---------------------------------------------------------------------------
__global__ void k_prep(const float* __restrict__ w,
                       const float* __restrict__ w_off,
                       const float* __restrict__ w_mod,
                       short* __restrict__ wt2, short* __restrict__ wc2) {
    int t = blockIdx.x * 256 + threadIdx.x;
    if (t < 9 * 64 * 64) {
        int c = t & 63, o = (t >> 6) & 63, f = t >> 12;
        wt2[t] = f2bf(w[(o * 64 + c) * 9 + f]);
    }
    int u = t - 9 * 64 * 64;
    if (u >= 0 && u < 9 * 32 * 64) {
        int c = u & 63, ch = (u >> 6) & 31, f = u >> 11;
        float v = 0.f;
        if (ch < 18)      v = w_off[(ch * 64 + c) * 9 + f];
        else if (ch < 27) v = w_mod[((ch - 18) * 64 + c) * 9 + f];
        wc2[u] = f2bf(v);
    }
}

// ---------------------------------------------------------------------------
// Transpose x NCHW fp32 -> NHWC bf16 (xt[b][y][x][c]); block 256, grid B*H.
// Coalesced reads via LDS tile [c][x].
// ---------------------------------------------------------------------------
__global__ __launch_bounds__(256) void k_transpose(const float* __restrict__ x,
                                                   short* __restrict__ xt) {
    __shared__ float s[64 * 65];
    int tid = threadIdx.x;
    int by  = blockIdx.x;
    int b = by >> 6, y = by & 63;
    const float* xb = x + ((size_t)b * 64) * 4096 + y * 64;
    #pragma unroll
    for (int q = 0; q < 4; ++q) {
        int fi = q * 256 + tid;              // 0..1023
        int c = fi >> 4, xq = (fi & 15) * 4;
        float4 v = *(const float4*)(xb + (size_t)c * 4096 + xq);
        s[c * 65 + xq + 0] = v.x; s[c * 65 + xq + 1] = v.y;
        s[c * 65 + xq + 2] = v.z; s[c * 65 + xq + 3] = v.w;
    }
    __syncthreads();
    short* dst = xt + ((size_t)(b * 64 + y)) * 4096;
    #pragma unroll
    for (int q = 0; q < 4; ++q) {
        int fi = q * 256 + tid;
        int xx = fi >> 4, c = (fi & 15) * 4;
        short4 v = make_short4(f2bf(s[(c + 0) * 65 + xx]), f2bf(s[(c + 1) * 65 + xx]),
                               f2bf(s[(c + 2) * 65 + xx]), f2bf(s[(c + 3) * 65 + xx]));
        *(short4*)(dst + xx * 64 + c) = v;
    }
}

// ---------------------------------------------------------------------------
// Offset+mask 3x3 conv via MFMA, stage-once LDS.
// Block = 256 (4 waves) = one row (b,i). Stage rows i-1..i+1 bf16 [3][66][72]
// (x-padded), then all 9 taps from LDS. M=64 px, N=32 ch.
// Wave wv: n-frag (wv&1), m-frags {2*(wv>>1), +1}. raw[ch][pix] output.
// ---------------------------------------------------------------------------
__global__ __launch_bounds__(256) void k_conv(
        const short* __restrict__ xt, const short* __restrict__ wc2,
        const float* __restrict__ b_off, const float* __restrict__ b_mod,
        float* __restrict__ raw) {
    __shared__ __align__(16) char smem[28512];       // s_in[3][66][72]bf16; s_out[32][66]f32
    short* s_in  = (short*)smem;
    float* s_out = (float*)smem;

    int tid  = threadIdx.x;
    int lane = tid & 63;
    int wv   = __builtin_amdgcn_readfirstlane((int)(tid >> 6));
    int blk  = blockIdx.x;                           // b*64 + i
    int b = blk >> 6, i = blk & 63;
    const short* xs = xt + (size_t)b * (64 * 4096);

    // ---- stage 3 rows, zero-padded in x (stored px = actual x + 1)
    #pragma unroll
    for (int r = 0; r < 3; ++r) {
        int y = i - 1 + r;
        bool yok = (unsigned)y < 64u;
        const short* rowp = xs + (size_t)y * 4096;
        #pragma unroll
        for (int q = 0; q < 2; ++q) {
            int idx = q * 256 + tid;                 // 0..511
            int px = idx >> 3;
            int c  = (idx & 7) * 8;
            short8v v = yok ? *(const short8v*)(rowp + px * 64 + c)
                            : (short8v){0,0,0,0,0,0,0,0};
            *(short8v*)(s_in + (r * 66 + px + 1) * 72 + c) = v;
        }
        if (tid < 128) {
            int px = (tid >> 6) ? 65 : 0;
            s_in[(r * 66 + px) * 72 + lane] = 0;
        }
    }

    // ---- B-frags: wave's n-frag, all taps
    int nf = wv & 1, mg = wv >> 1;
    bf16x8 bfrag[9][2];
    {
        int o  = nf * 16 + (lane & 15);
        int cb = (lane >> 4) * 8;
        #pragma unroll
        for (int f = 0; f < 9; ++f)
            #pragma unroll
            for (int kk = 0; kk < 2; ++kk)
                bfrag[f][kk] = *(const bf16x8*)(wc2 + (f * 32 + o) * 64 + kk * 32 + cb);
    }

    f32x4 acc[2];
    #pragma unroll
    for (int m = 0; m < 2; ++m) acc[m] = (f32x4){0.f, 0.f, 0.f, 0.f};

    __syncthreads();
    int arow = lane & 15, acolb = (lane >> 4) * 8;
    #pragma unroll
    for (int ky = 0; ky < 3; ++ky)
        #pragma unroll
        for (int kx = 0; kx < 3; ++kx) {
            int f = ky * 3 + kx;
            #pragma unroll
            for (int kk = 0; kk < 2; ++kk)
                #pragma unroll
                for (int mm = 0; mm < 2; ++mm) {
                    const short* ap = s_in + (ky * 66 + mg * 32 + mm * 16 + arow + kx) * 72
                                    + kk * 32 + acolb;
                    acc[mm] = __builtin_amdgcn_mfma_f32_16x16x32_bf16(
                        *(const bf16x8*)ap, bfrag[f][kk], acc[mm], 0, 0, 0);
                }
        }
    __syncthreads();                                 // done reading s_in
    {   // acc -> s_out[ch][p]
        int oc = nf * 16 + (lane & 15);
        int pr = (lane >> 4) * 4;
        #pragma unroll
        for (int mm = 0; mm < 2; ++mm)
            #pragma unroll
            for (int r = 0; r < 4; ++r)
                s_out[oc * 66 + mg * 32 + mm * 16 + pr + r] = acc[mm][r];
    }
    __syncthreads();
    int pixBase = blk * 64;
    #pragma unroll
    for (int u = tid; u < 27 * 64; u += 256) {
        int ch = u >> 6, p = u & 63;
        float bv = ch < 18 ? b_off[ch] : b_mod[ch - 18];
        raw[(size_t)ch * NPIX + pixBase + p] = s_out[ch * 66 + p] + bv;
    }
}

// ---------------------------------------------------------------------------
// Bilinear metadata, thread = (tap, pixel), fully coalesced. Grid 1152.
// ---------------------------------------------------------------------------
__global__ __launch_bounds__(256) void k_meta(const float* __restrict__ raw,
                       float4* __restrict__ metaW, int4* __restrict__ metaO) {
    int t = blockIdx.x * 256 + threadIdx.x;          // 0 .. 294911
    int f   = t >> 15;
    int pix = t & 32767;
    int j = pix & 63, i = (pix >> 6) & 63;

    float dy = raw[(size_t)(2 * f)     * NPIX + pix];
    float dx = raw[(size_t)(2 * f + 1) * NPIX + pix];
    float mv = raw[(size_t)(18 + f)    * NPIX + pix];
    float m  = 1.f / (1.f + expf(-mv));

    float ys = (float)(i - 1 + f / 3) + dy;
    float xs = (float)(j - 1 + f % 3) + dx;
    float y0f = floorf(ys), x0f = floorf(xs);
    int   y0  = (int)y0f,   x0  = (int)x0f;
    float fy = ys - y0f, fx = xs - x0f;

    bool vy0 = (unsigned)y0       < 64u, vy1 = (unsigned)(y0 + 1) < 64u;
    bool vx0 = (unsigned)x0       < 64u, vx1 = (unsigned)(x0 + 1) < 64u;
    float w00 = (vy0 & vx0) ? (1.f - fy) * (1.f - fx) * m : 0.f;
    float w01 = (vy0 & vx1) ? (1.f - fy) * fx         * m : 0.f;
    float w10 = (vy1 & vx0) ? fy         * (1.f - fx) * m : 0.f;
    float w11 = (vy1 & vx1) ? fy         * fx         * m : 0.f;

    int y0c = min(max(y0, 0), 63), y1c = min(max(y0 + 1, 0), 63);
    int x0c = min(max(x0, 0), 63), x1c = min(max(x0 + 1, 0), 63);

    metaW[t] = make_float4(w00, w01, w10, w11);
    metaO[t] = make_int4((y0c * 64 + x0c) * 64, (y0c * 64 + x1c) * 64,
                         (y1c * 64 + x0c) * 64, (y1c * 64 + x1c) * 64);
}

// ---------------------------------------------------------------------------
// Main deformable conv: block 256 = half row (b,i,half), 32 px x 64 Cout.
// Grid 1024. T14 async-split: gather tap f+1 into regs while MFMA tap f.
// Wave wv owns n-frag wv (16 ch) and gathers pixels [wv*8, +8).
// ---------------------------------------------------------------------------
__global__ __launch_bounds__(256) void k_main(
        const short* __restrict__ xt,
        const float4* __restrict__ metaW, const int4* __restrict__ metaO,
        const short* __restrict__ wt2, const float* __restrict__ bias,
        float* __restrict__ out) {
    __shared__ __align__(16) char smem[8448];        // s_a[32][72]bf16=4608; s_out[32][66]f32=8448
    short* s_a   = (short*)smem;
    float* s_out = (float*)smem;

    int tid  = threadIdx.x;
    int lane = tid & 63;
    int wv   = __builtin_amdgcn_readfirstlane((int)(tid >> 6));
    int blk  = blockIdx.x;                           // (b*64+i)*2 + half
    int pixBase = blk * 32;
    int b = blk >> 7, i = (blk >> 1) & 63, half = blk & 1;
    const short* xb = xt + (size_t)b * (64 * 4096);
    int orange = wv * 16;

    bf16x8 bfrag[9][2];
    {
        int o  = orange + (lane & 15);
        int cb = (lane >> 4) * 8;
        #pragma unroll
        for (int f = 0; f < 9; ++f)
            #pragma unroll
            for (int kk = 0; kk < 2; ++kk)
                bfrag[f][kk] = *(const bf16x8*)(wt2 + (f * 64 + o) * 64 + kk * 32 + cb);
    }

    f32x4 acc[2];
    #pragma unroll
    for (int m = 0; m < 2; ++m) acc[m] = (f32x4){0.f, 0.f, 0.f, 0.f};

    float sv[8];
    #define GATHER(F) {                                                        \
        _Pragma("unroll")                                                      \
        for (int p8 = 0; p8 < 8; ++p8) {                                       \
            int mi = (F) * NPIX + pixBase + wv * 8 + p8;  /* wave-uniform */   \
            float4 wts = metaW[mi];                                            \
            int4   off = metaO[mi];                                            \
            sv[p8] = wts.x * bf2f(xb[off.x + lane])                            \
                   + wts.y * bf2f(xb[off.y + lane])                            \
                   + wts.z * bf2f(xb[off.z + lane])                            \
                   + wts.w * bf2f(xb[off.w + lane]);                           \
        } }
    #define WRITE() {                                                          \
        _Pragma("unroll")                                                      \
        for (int p8 = 0; p8 < 8; ++p8)                                         \
            s_a[(wv * 8 + p8) * 72 + lane] = f2bf(sv[p8]);                     \
        }

    GATHER(0); WRITE();
    __syncthreads();
    int arow = lane & 15, acolb = (lane >> 4) * 8;
    for (int f = 0; f < 9; ++f) {
        if (f < 8) GATHER(f + 1);                    // loads fly during MFMA
        #pragma unroll
        for (int kk = 0; kk < 2; ++kk)
            #pragma unroll
            for (int m = 0; m < 2; ++m) {
                bf16x8 af = *(const bf16x8*)(s_a + (m * 16 + arow) * 72 + kk * 32 + acolb);
                acc[m] = __builtin_amdgcn_mfma_f32_16x16x32_bf16(af, bfrag[f][kk], acc[m], 0, 0, 0);
            }
        __syncthreads();                             // all reads of s_a done
        if (f < 8) { WRITE(); __syncthreads(); }
    }
    {   // acc -> s_out[p][o]
        int oc = lane & 15;
        int pr = (lane >> 4) * 4;
        #pragma unroll
        for (int m = 0; m < 2; ++m)
            #pragma unroll
            for (int r = 0; r < 4; ++r)
                s_out[(m * 16 + pr + r) * 66 + orange + oc] = acc[m][r];
    }
    __syncthreads();
    #pragma unroll
    for (int u = tid; u < 64 * 32; u += 256) {
        int o = u >> 5, p = u & 31;
        out[(((size_t)b * 64 + o) * 64 + i) * 64 + half * 32 + p] = s_out[p * 66 + o] + bias[o];
    }
    #undef GATHER
    #undef WRITE
}

// ---------------------------------------------------------------------------
extern "C" void kernel_launch(void* const* d_in, const int* in_sizes, int n_in,
                              void* d_out, int out_size, void* d_ws, size_t ws_size,
                              hipStream_t stream) {
    const float* x     = (const float*)d_in[0];
    const float* w_off = (const float*)d_in[1];
    const float* b_off = (const float*)d_in[2];
    const float* w_mod = (const float*)d_in[3];
    const float* b_mod = (const float*)d_in[4];
    const float* w     = (const float*)d_in[5];
    const float* bias  = (const float*)d_in[6];
    float* out = (float*)d_out;

    char* ws = (char*)d_ws;
    short*  xt    = (short*)(ws);                    //  4,194,304 B
    float*  raw   = (float*)(ws + 4194304);          //  3,538,944 B
    float4* metaW = (float4*)(ws + 7733248);         //  4,718,592 B
    int4*   metaO = (int4*)(ws + 12451840);          //  4,718,592 B
    short*  wt2   = (short*)(ws + 17170432);         //     73,728 B
    short*  wc2   = (short*)(ws + 17244160);         //     36,864 B

    hipLaunchKernelGGL(k_prep,      dim3(216),  dim3(256), 0, stream, w, w_off, w_mod, wt2, wc2);
    hipLaunchKernelGGL(k_transpose, dim3(512),  dim3(256), 0, stream, x, xt);
    hipLaunchKernelGGL(k_conv,      dim3(512),  dim3(256), 0, stream, xt, wc2, b_off, b_mod, raw);
    hipLaunchKernelGGL(k_meta,      dim3(1152), dim3(256), 0, stream, raw, metaW, metaO);
    hipLaunchKernelGGL(k_main,      dim3(1024), dim3(256), 0, stream,
                       xt, metaW, metaO, wt2, bias, out);
}

// Round 4
// 63.272 us; speedup vs baseline: 2.5948x; 1.0407x over previous
//
#include <hip/hip_runtime.h>
#include <math.h>

#define HW    64
#define CIN   64
#define COUT  64
#define BATCH 8
#define KK    9
#define NPIX  (BATCH*HW*HW)      // 32768

typedef __attribute__((ext_vector_type(8))) short bf16x8;
typedef __attribute__((ext_vector_type(8))) short short8v;
typedef __attribute__((ext_vector_type(4))) float f32x4;

static __device__ inline short f2bf(float f) {
    union { float f; unsigned u; } v; v.f = f;
    unsigned r = v.u + 0x7fff + ((v.u >> 16) & 1);   // RNE
    return (short)(r >> 16);
}
static __device__ inline float bf2f(short s) {
    union { unsigned u; float f; } v; v.u = ((unsigned)(unsigned short)s) << 16;
    return v.f;
}

// ---------------------------------------------------------------------------
// Prep: wt2[f][o][c] bf16 (main weight), wc2[f][ch32][c] bf16 (off+mod, pad 32)
// ---------------------------------------------------------------------------
__global__ void k_prep(const float* __restrict__ w,
                       const float* __restrict__ w_off,
                       const float* __restrict__ w_mod,
                       short* __restrict__ wt2, short* __restrict__ wc2) {
    int t = blockIdx.x * 256 + threadIdx.x;
    if (t < 9 * 64 * 64) {
        int c = t & 63, o = (t >> 6) & 63, f = t >> 12;
        wt2[t] = f2bf(w[(o * 64 + c) * 9 + f]);
    }
    int u = t - 9 * 64 * 64;
    if (u >= 0 && u < 9 * 32 * 64) {
        int c = u & 63, ch = (u >> 6) & 31, f = u >> 11;
        float v = 0.f;
        if (ch < 18)      v = w_off[(ch * 64 + c) * 9 + f];
        else if (ch < 27) v = w_mod[((ch - 18) * 64 + c) * 9 + f];
        wc2[u] = f2bf(v);
    }
}

// ---------------------------------------------------------------------------
// Transpose x NCHW fp32 -> NHWC bf16 (xt[b][y][x][c]); block 256, grid B*H.
// ---------------------------------------------------------------------------
__global__ __launch_bounds__(256) void k_transpose(const float* __restrict__ x,
                                                   short* __restrict__ xt) {
    __shared__ float s[64 * 65];
    int tid = threadIdx.x;
    int by  = blockIdx.x;
    int b = by >> 6, y = by & 63;
    const float* xb = x + ((size_t)b * 64) * 4096 + y * 64;
    #pragma unroll
    for (int q = 0; q < 4; ++q) {
        int fi = q * 256 + tid;
        int c = fi >> 4, xq = (fi & 15) * 4;
        float4 v = *(const float4*)(xb + (size_t)c * 4096 + xq);
        s[c * 65 + xq + 0] = v.x; s[c * 65 + xq + 1] = v.y;
        s[c * 65 + xq + 2] = v.z; s[c * 65 + xq + 3] = v.w;
    }
    __syncthreads();
    short* dst = xt + ((size_t)(b * 64 + y)) * 4096;
    #pragma unroll
    for (int q = 0; q < 4; ++q) {
        int fi = q * 256 + tid;
        int xx = fi >> 4, c = (fi & 15) * 4;
        short4 v = make_short4(f2bf(s[(c + 0) * 65 + xx]), f2bf(s[(c + 1) * 65 + xx]),
                               f2bf(s[(c + 2) * 65 + xx]), f2bf(s[(c + 3) * 65 + xx]));
        *(short4*)(dst + xx * 64 + c) = v;
    }
}

// ---------------------------------------------------------------------------
// Offset+mask 3x3 conv via MFMA (stage-once LDS) + FUSED bilinear metadata.
// Block = 256 (4 waves) = one row (b,i). Outputs metaW/metaO directly.
// ---------------------------------------------------------------------------
__global__ __launch_bounds__(256) void k_conv(
        const short* __restrict__ xt, const short* __restrict__ wc2,
        const float* __restrict__ b_off, const float* __restrict__ b_mod,
        float4* __restrict__ metaW, int4* __restrict__ metaO) {
    __shared__ __align__(16) char smem[28512];       // s_in[3][66][72]bf16; s_out[32][66]f32
    short* s_in  = (short*)smem;
    float* s_out = (float*)smem;

    int tid  = threadIdx.x;
    int lane = tid & 63;
    int wv   = __builtin_amdgcn_readfirstlane((int)(tid >> 6));
    int blk  = blockIdx.x;                           // b*64 + i
    int b = blk >> 6, i = blk & 63;
    const short* xs = xt + (size_t)b * (64 * 4096);

    // ---- stage 3 rows, zero-padded in x (stored px = actual x + 1)
    #pragma unroll
    for (int r = 0; r < 3; ++r) {
        int y = i - 1 + r;
        bool yok = (unsigned)y < 64u;
        const short* rowp = xs + (size_t)y * 4096;
        #pragma unroll
        for (int q = 0; q < 2; ++q) {
            int idx = q * 256 + tid;
            int px = idx >> 3;
            int c  = (idx & 7) * 8;
            short8v v = yok ? *(const short8v*)(rowp + px * 64 + c)
                            : (short8v){0,0,0,0,0,0,0,0};
            *(short8v*)(s_in + (r * 66 + px + 1) * 72 + c) = v;
        }
        if (tid < 128) {
            int px = (tid >> 6) ? 65 : 0;
            s_in[(r * 66 + px) * 72 + lane] = 0;
        }
    }

    int nf = wv & 1, mg = wv >> 1;
    bf16x8 bfrag[9][2];
    {
        int o  = nf * 16 + (lane & 15);
        int cb = (lane >> 4) * 8;
        #pragma unroll
        for (int f = 0; f < 9; ++f)
            #pragma unroll
            for (int kk = 0; kk < 2; ++kk)
                bfrag[f][kk] = *(const bf16x8*)(wc2 + (f * 32 + o) * 64 + kk * 32 + cb);
    }

    f32x4 acc[2];
    #pragma unroll
    for (int m = 0; m < 2; ++m) acc[m] = (f32x4){0.f, 0.f, 0.f, 0.f};

    __syncthreads();
    int arow = lane & 15, acolb = (lane >> 4) * 8;
    #pragma unroll
    for (int ky = 0; ky < 3; ++ky)
        #pragma unroll
        for (int kx = 0; kx < 3; ++kx) {
            int f = ky * 3 + kx;
            #pragma unroll
            for (int kk = 0; kk < 2; ++kk)
                #pragma unroll
                for (int mm = 0; mm < 2; ++mm) {
                    const short* ap = s_in + (ky * 66 + mg * 32 + mm * 16 + arow + kx) * 72
                                    + kk * 32 + acolb;
                    acc[mm] = __builtin_amdgcn_mfma_f32_16x16x32_bf16(
                        *(const bf16x8*)ap, bfrag[f][kk], acc[mm], 0, 0, 0);
                }
        }
    __syncthreads();                                 // done reading s_in
    {   // acc -> s_out[ch][p]
        int oc = nf * 16 + (lane & 15);
        int pr = (lane >> 4) * 4;
        #pragma unroll
        for (int mm = 0; mm < 2; ++mm)
            #pragma unroll
            for (int r = 0; r < 4; ++r)
                s_out[oc * 66 + mg * 32 + mm * 16 + pr + r] = acc[mm][r];
    }
    __syncthreads();

    // ---- fused metadata: (f,p) pairs from s_out
    int pixBase = blk * 64;
    for (int u = tid; u < 9 * 64; u += 256) {
        int f = u >> 6, p = u & 63;
        float dy = s_out[(2 * f)     * 66 + p] + b_off[2 * f];
        float dx = s_out[(2 * f + 1) * 66 + p] + b_off[2 * f + 1];
        float mv = s_out[(18 + f)    * 66 + p] + b_mod[f];
        float m  = 1.f / (1.f + expf(-mv));

        float ys = (float)(i - 1 + f / 3) + dy;
        float xs2 = (float)(p - 1 + f % 3) + dx;
        float y0f = floorf(ys), x0f = floorf(xs2);
        int   y0  = (int)y0f,   x0  = (int)x0f;
        float fy = ys - y0f, fx = xs2 - x0f;

        bool vy0 = (unsigned)y0       < 64u, vy1 = (unsigned)(y0 + 1) < 64u;
        bool vx0 = (unsigned)x0       < 64u, vx1 = (unsigned)(x0 + 1) < 64u;
        float w00 = (vy0 & vx0) ? (1.f - fy) * (1.f - fx) * m : 0.f;
        float w01 = (vy0 & vx1) ? (1.f - fy) * fx         * m : 0.f;
        float w10 = (vy1 & vx0) ? fy         * (1.f - fx) * m : 0.f;
        float w11 = (vy1 & vx1) ? fy         * fx         * m : 0.f;

        int y0c = min(max(y0, 0), 63), y1c = min(max(y0 + 1, 0), 63);
        int x0c = min(max(x0, 0), 63), x1c = min(max(x0 + 1, 0), 63);

        metaW[f * NPIX + pixBase + p] = make_float4(w00, w01, w10, w11);
        metaO[f * NPIX + pixBase + p] = make_int4((y0c * 64 + x0c) * 64, (y0c * 64 + x1c) * 64,
                                                  (y1c * 64 + x0c) * 64, (y1c * 64 + x1c) * 64);
    }
}

// ---------------------------------------------------------------------------
// Main deformable conv, operand-swapped: out^T[o][px] = W[o][ck] * S^T[ck][px].
// Block = 128 (2 waves: kk=0/1 halves of K), 16 pixels, all 64 Cout.
// No LDS / no barriers in the tap loop: B-frag (sampled) is gathered straight
// into registers (col=lane&15=pixel, k=(lane>>4)*8 contiguous channels);
// A-frags (weights) stream from global (L1/L2-resident, prefetchable).
// Grid 2048 -> 16 waves/CU, waves fully independent.
// ---------------------------------------------------------------------------
__global__ __launch_bounds__(128, 4) void k_main(
        const short* __restrict__ xt,
        const float4* __restrict__ metaW, const int4* __restrict__ metaO,
        const short* __restrict__ wt2, const float* __restrict__ bias,
        float* __restrict__ out) {
    __shared__ float s_red[2][64 * 17];              // [kk][o*17 + px]

    int tid  = threadIdx.x;
    int lane = tid & 63;
    int kk   = __builtin_amdgcn_readfirstlane((int)(tid >> 6));
    int blk  = blockIdx.x;                           // pix/16
    int pixBase = blk * 16;
    int b = blk >> 8;
    const short* xb = xt + (size_t)b * (64 * 4096);
    int pxl = lane & 15;
    int cg  = lane >> 4;
    int px  = pixBase + pxl;
    int choff = kk * 32 + cg * 8;                    // element offset in corner row

    f32x4 acc[4];
    #pragma unroll
    for (int mf = 0; mf < 4; ++mf) acc[mf] = (f32x4){0.f, 0.f, 0.f, 0.f};

    #pragma unroll
    for (int f = 0; f < 9; ++f) {
        float4 wts = metaW[f * NPIX + px];
        int4   off = metaO[f * NPIX + px];
        bf16x8 c0 = *(const bf16x8*)(xb + off.x + choff);
        bf16x8 c1 = *(const bf16x8*)(xb + off.y + choff);
        bf16x8 c2 = *(const bf16x8*)(xb + off.z + choff);
        bf16x8 c3 = *(const bf16x8*)(xb + off.w + choff);
        bf16x8 sf;
        #pragma unroll
        for (int j = 0; j < 8; ++j) {
            float s = wts.x * bf2f(c0[j]) + wts.y * bf2f(c1[j])
                    + wts.z * bf2f(c2[j]) + wts.w * bf2f(c3[j]);
            sf[j] = f2bf(s);
        }
        const short* wp = wt2 + (size_t)(f * 64 + pxl) * 64 + choff;
        #pragma unroll
        for (int mf = 0; mf < 4; ++mf) {
            bf16x8 wf = *(const bf16x8*)(wp + mf * 16 * 64);
            acc[mf] = __builtin_amdgcn_mfma_f32_16x16x32_bf16(wf, sf, acc[mf], 0, 0, 0);
        }
    }

    // epilogue: cross-kk reduce via LDS, then coalesced store
    #pragma unroll
    for (int mf = 0; mf < 4; ++mf)
        #pragma unroll
        for (int r = 0; r < 4; ++r)
            s_red[kk][(mf * 16 + cg * 4 + r) * 17 + pxl] = acc[mf][r];
    __syncthreads();
    {
        int o  = tid >> 1;
        int p8 = (tid & 1) * 8;
        int i  = (blk >> 2) & 63;
        int jb = (blk & 3) * 16;
        float bv = bias[o];
        float* op = out + ((size_t)(b * 64) + o) * 4096 + i * 64 + jb + p8;
        float4 v0, v1;
        v0.x = s_red[0][o * 17 + p8 + 0] + s_red[1][o * 17 + p8 + 0] + bv;
        v0.y = s_red[0][o * 17 + p8 + 1] + s_red[1][o * 17 + p8 + 1] + bv;
        v0.z = s_red[0][o * 17 + p8 + 2] + s_red[1][o * 17 + p8 + 2] + bv;
        v0.w = s_red[0][o * 17 + p8 + 3] + s_red[1][o * 17 + p8 + 3] + bv;
        v1.x = s_red[0][o * 17 + p8 + 4] + s_red[1][o * 17 + p8 + 4] + bv;
        v1.y = s_red[0][o * 17 + p8 + 5] + s_red[1][o * 17 + p8 + 5] + bv;
        v1.z = s_red[0][o * 17 + p8 + 6] + s_red[1][o * 17 + p8 + 6] + bv;
        v1.w = s_red[0][o * 17 + p8 + 7] + s_red[1][o * 17 + p8 + 7] + bv;
        *(float4*)op       = v0;
        *(float4*)(op + 4) = v1;
    }
}

// ---------------------------------------------------------------------------
extern "C" void kernel_launch(void* const* d_in, const int* in_sizes, int n_in,
                              void* d_out, int out_size, void* d_ws, size_t ws_size,
                              hipStream_t stream) {
    const float* x     = (const float*)d_in[0];
    const float* w_off = (const float*)d_in[1];
    const float* b_off = (const float*)d_in[2];
    const float* w_mod = (const float*)d_in[3];
    const float* b_mod = (const float*)d_in[4];
    const float* w     = (const float*)d_in[5];
    const float* bias  = (const float*)d_in[6];
    float* out = (float*)d_out;

    char* ws = (char*)d_ws;
    short*  xt    = (short*)(ws);                    //  4,194,304 B
    float4* metaW = (float4*)(ws + 4194304);         //  4,718,592 B
    int4*   metaO = (int4*)(ws + 8912896);           //  4,718,592 B
    short*  wt2   = (short*)(ws + 13631488);         //     73,728 B
    short*  wc2   = (short*)(ws + 13705216);         //     36,864 B

    hipLaunchKernelGGL(k_prep,      dim3(216),  dim3(256), 0, stream, w, w_off, w_mod, wt2, wc2);
    hipLaunchKernelGGL(k_transpose, dim3(512),  dim3(256), 0, stream, x, xt);
    hipLaunchKernelGGL(k_conv,      dim3(512),  dim3(256), 0, stream,
                       xt, wc2, b_off, b_mod, metaW, metaO);
    hipLaunchKernelGGL(k_main,      dim3(2048), dim3(128), 0, stream,
                       xt, metaW, metaO, wt2, bias, out);
}

// Round 5
// 57.423 us; speedup vs baseline: 2.8591x; 1.1019x over previous
//
#include <hip/hip_runtime.h>
#include <math.h>

#define HW    64
#define NPIX  32768

typedef __attribute__((ext_vector_type(8))) short bf16x8;
typedef __attribute__((ext_vector_type(8))) short short8v;
typedef __attribute__((ext_vector_type(4))) float f32x4;

static __device__ inline short f2bf(float f) {
    union { float f; unsigned u; } v; v.f = f;
    unsigned r = v.u + 0x7fff + ((v.u >> 16) & 1);   // RNE
    return (short)(r >> 16);
}
static __device__ inline float bf2f(short s) {
    union { unsigned u; float f; } v; v.u = ((unsigned)(unsigned short)s) << 16;
    return v.f;
}

// ---------------------------------------------------------------------------
// Prep: wt2[f][o][c] bf16 (main weight), wc2[f][ch32][c] bf16 (off+mod, pad 32)
// ---------------------------------------------------------------------------
__global__ void k_prep(const float* __restrict__ w,
                       const float* __restrict__ w_off,
                       const float* __restrict__ w_mod,
                       short* __restrict__ wt2, short* __restrict__ wc2) {
    int t = blockIdx.x * 256 + threadIdx.x;
    if (t < 9 * 64 * 64) {
        int c = t & 63, o = (t >> 6) & 63, f = t >> 12;
        wt2[t] = f2bf(w[(o * 64 + c) * 9 + f]);
    }
    int u = t - 9 * 64 * 64;
    if (u >= 0 && u < 9 * 32 * 64) {
        int c = u & 63, ch = (u >> 6) & 31, f = u >> 11;
        float v = 0.f;
        if (ch < 18)      v = w_off[(ch * 64 + c) * 9 + f];
        else if (ch < 27) v = w_mod[((ch - 18) * 64 + c) * 9 + f];
        wc2[u] = f2bf(v);
    }
}

// ---------------------------------------------------------------------------
// Transpose x NCHW fp32 -> NHWC bf16 (xt[b][y][x][c]); block 256, grid B*H.
// ---------------------------------------------------------------------------
__global__ __launch_bounds__(256) void k_transpose(const float* __restrict__ x,
                                                   short* __restrict__ xt) {
    __shared__ float s[64 * 65];
    int tid = threadIdx.x;
    int by  = blockIdx.x;
    int b = by >> 6, y = by & 63;
    const float* xb = x + ((size_t)b * 64) * 4096 + y * 64;
    #pragma unroll
    for (int q = 0; q < 4; ++q) {
        int fi = q * 256 + tid;
        int c = fi >> 4, xq = (fi & 15) * 4;
        float4 v = *(const float4*)(xb + (size_t)c * 4096 + xq);
        s[c * 65 + xq + 0] = v.x; s[c * 65 + xq + 1] = v.y;
        s[c * 65 + xq + 2] = v.z; s[c * 65 + xq + 3] = v.w;
    }
    __syncthreads();
    short* dst = xt + ((size_t)(b * 64 + y)) * 4096;
    #pragma unroll
    for (int q = 0; q < 4; ++q) {
        int fi = q * 256 + tid;
        int xx = fi >> 4, c = (fi & 15) * 4;
        short4 v = make_short4(f2bf(s[(c + 0) * 65 + xx]), f2bf(s[(c + 1) * 65 + xx]),
                               f2bf(s[(c + 2) * 65 + xx]), f2bf(s[(c + 3) * 65 + xx]));
        *(short4*)(dst + xx * 64 + c) = v;
    }
}

// ---------------------------------------------------------------------------
// FUSED kernel: per half-row (b, i, jb): stage 3 xt rows -> offset/mask conv
// (MFMA) -> bilinear meta (kept in LDS) -> deformable gather (global xt,
// register B-frags) -> main MFMA (out^T = W x S^T) -> transpose+store.
// Block = 128 (2 waves), each wave: conv ch-half, then 16 px full-K main.
// Grid = 1024 (4 blocks/CU).
// ---------------------------------------------------------------------------
__global__ __launch_bounds__(128, 2) void k_fused(
        const short* __restrict__ xt,
        const short* __restrict__ wc2, const short* __restrict__ wt2,
        const float* __restrict__ b_off, const float* __restrict__ b_mod,
        const float* __restrict__ bias, float* __restrict__ out) {
    // region A (aliased across phases): s_in [3][34][72]bf16 = 14688
    //   -> meta: s_mW[288]f4 (4608) + s_mO[288]i4 (4608)  -> s_fin[64][33]f32 (8448)
    // region B: s_out [32][36]f32 = 4608
    __shared__ __align__(16) char smem[19328];
    short*  s_in  = (short*)smem;
    float4* s_mW  = (float4*)smem;
    int4*   s_mO  = (int4*)(smem + 4608);
    float*  s_fin = (float*)smem;
    float*  s_out = (float*)(smem + 14720);

    int tid  = threadIdx.x;
    int lane = tid & 63;
    int wv   = __builtin_amdgcn_readfirstlane((int)(tid >> 6));
    int blk  = blockIdx.x;                     // (b*64+i)*2 + half
    int b = blk >> 7, i = (blk >> 1) & 63, jb = (blk & 1) * 32;
    const short* xb = xt + (size_t)b * 262144;

    int arow = lane & 15;                      // frag row / pixel-in-frag
    int cg   = lane >> 4;                      // k-group 0..3
    int cgb  = cg * 8;

    // ---- phase 1: stage 3 rows x 34 px x 64 ch (zero-padded outside image)
    for (int u = tid; u < 816; u += 128) {     // 816 = 3*34*8
        int r = u / 272, rem = u - r * 272;
        int slot = rem >> 3, c8 = (rem & 7) << 3;
        int y = i - 1 + r, gx = jb + slot - 1;
        short8v v = (short8v){0,0,0,0,0,0,0,0};
        if (((unsigned)y < 64u) & ((unsigned)gx < 64u))
            v = *(const short8v*)(xb + ((y << 6) + gx) * 64 + c8);
        *(short8v*)(s_in + (r * 34 + slot) * 72 + c8) = v;
    }
    __syncthreads();

    // ---- phase 2: offset/mask conv. wave wv owns ch [wv*16,+16), px 0..31.
    f32x4 accc[2];
    accc[0] = (f32x4){0.f,0.f,0.f,0.f};
    accc[1] = (f32x4){0.f,0.f,0.f,0.f};
    #pragma unroll
    for (int ky = 0; ky < 3; ++ky)
        #pragma unroll
        for (int kx = 0; kx < 3; ++kx) {
            int f = ky * 3 + kx;
            bf16x8 bq[2];
            #pragma unroll
            for (int kk = 0; kk < 2; ++kk)
                bq[kk] = *(const bf16x8*)(wc2 + (f * 32 + wv * 16 + arow) * 64 + kk * 32 + cgb);
            #pragma unroll
            for (int kk = 0; kk < 2; ++kk)
                #pragma unroll
                for (int mm = 0; mm < 2; ++mm) {
                    const short* ap = s_in + (ky * 34 + mm * 16 + arow + kx) * 72 + kk * 32 + cgb;
                    accc[mm] = __builtin_amdgcn_mfma_f32_16x16x32_bf16(
                        *(const bf16x8*)ap, bq[kk], accc[mm], 0, 0, 0);
                }
        }
    {   // accc -> s_out[ch][px]   (col=lane&15 = ch, row=(lane>>4)*4+r = px)
        int ch = wv * 16 + arow;
        #pragma unroll
        for (int mm = 0; mm < 2; ++mm)
            #pragma unroll
            for (int r = 0; r < 4; ++r)
                s_out[ch * 36 + mm * 16 + cg * 4 + r] = accc[mm][r];
    }
    __syncthreads();                            // s_in dead; s_out ready

    // ---- phase 3: bilinear meta for 9 taps x 32 px -> LDS (aliases s_in)
    for (int u = tid; u < 288; u += 128) {
        int f = u >> 5, p = u & 31;
        float dy = s_out[(2 * f)     * 36 + p] + b_off[2 * f];
        float dx = s_out[(2 * f + 1) * 36 + p] + b_off[2 * f + 1];
        float mv = s_out[(18 + f)    * 36 + p] + b_mod[f];
        float m  = 1.f / (1.f + expf(-mv));

        float ys  = (float)(i - 1 + f / 3) + dy;
        float xs2 = (float)(jb + p - 1 + f % 3) + dx;
        float y0f = floorf(ys), x0f = floorf(xs2);
        int   y0  = (int)y0f,   x0  = (int)x0f;
        float fy = ys - y0f, fx = xs2 - x0f;

        bool vy0 = (unsigned)y0       < 64u, vy1 = (unsigned)(y0 + 1) < 64u;
        bool vx0 = (unsigned)x0       < 64u, vx1 = (unsigned)(x0 + 1) < 64u;
        float w00 = (vy0 & vx0) ? (1.f - fy) * (1.f - fx) * m : 0.f;
        float w01 = (vy0 & vx1) ? (1.f - fy) * fx         * m : 0.f;
        float w10 = (vy1 & vx0) ? fy         * (1.f - fx) * m : 0.f;
        float w11 = (vy1 & vx1) ? fy         * fx         * m : 0.f;

        int y0c = min(max(y0, 0), 63), y1c = min(max(y0 + 1, 0), 63);
        int x0c = min(max(x0, 0), 63), x1c = min(max(x0 + 1, 0), 63);

        s_mW[u] = make_float4(w00, w01, w10, w11);
        s_mO[u] = make_int4((y0c * 64 + x0c) * 64, (y0c * 64 + x1c) * 64,
                            (y1c * 64 + x0c) * 64, (y1c * 64 + x1c) * 64);
    }
    __syncthreads();                            // meta ready

    // ---- phase 4: deformable gather + main MFMA (out^T = W * S^T).
    // wave wv owns px [wv*16,+16); lane gathers pixel arow, k-chunk cg.
    f32x4 acc[4];
    #pragma unroll
    for (int mf = 0; mf < 4; ++mf) acc[mf] = (f32x4){0.f,0.f,0.f,0.f};

    #pragma unroll
    for (int f = 0; f < 9; ++f) {
        int mi = f * 32 + wv * 16 + arow;       // LDS, broadcast across cg
        float4 mW = s_mW[mi];
        int4   mO = s_mO[mi];
        bf16x8 c0[2], c1[2], c2[2], c3[2];
        #pragma unroll
        for (int kk = 0; kk < 2; ++kk) {
            int base = kk * 32 + cgb;
            c0[kk] = *(const bf16x8*)(xb + mO.x + base);
            c1[kk] = *(const bf16x8*)(xb + mO.y + base);
            c2[kk] = *(const bf16x8*)(xb + mO.z + base);
            c3[kk] = *(const bf16x8*)(xb + mO.w + base);
        }
        bf16x8 sf[2];
        #pragma unroll
        for (int kk = 0; kk < 2; ++kk)
            #pragma unroll
            for (int j = 0; j < 8; ++j) {
                float s = mW.x * bf2f(c0[kk][j]) + mW.y * bf2f(c1[kk][j])
                        + mW.z * bf2f(c2[kk][j]) + mW.w * bf2f(c3[kk][j]);
                sf[kk][j] = f2bf(s);
            }
        #pragma unroll
        for (int kk = 0; kk < 2; ++kk)
            #pragma unroll
            for (int mf = 0; mf < 4; ++mf) {
                const short* wp = wt2 + (f * 64 + mf * 16 + arow) * 64 + kk * 32 + cgb;
                acc[mf] = __builtin_amdgcn_mfma_f32_16x16x32_bf16(
                    *(const bf16x8*)wp, sf[kk], acc[mf], 0, 0, 0);
            }
    }
    __syncthreads();                            // meta dead; s_fin aliases

    // ---- phase 5: acc (col=px, row=o) -> s_fin[o][px] -> coalesced store
    #pragma unroll
    for (int mf = 0; mf < 4; ++mf)
        #pragma unroll
        for (int r = 0; r < 4; ++r)
            s_fin[(mf * 16 + cg * 4 + r) * 33 + wv * 16 + arow] = acc[mf][r];
    __syncthreads();
    {
        int o  = tid >> 1;
        int ph = (tid & 1) * 16;
        float bv = bias[o];
        float* op = out + (((size_t)(b * 64 + o)) * 64 + i) * 64 + jb + ph;
        #pragma unroll
        for (int q = 0; q < 4; ++q) {
            float4 v;
            v.x = s_fin[o * 33 + ph + q * 4 + 0] + bv;
            v.y = s_fin[o * 33 + ph + q * 4 + 1] + bv;
            v.z = s_fin[o * 33 + ph + q * 4 + 2] + bv;
            v.w = s_fin[o * 33 + ph + q * 4 + 3] + bv;
            *(float4*)(op + q * 4) = v;
        }
    }
}

// ---------------------------------------------------------------------------
extern "C" void kernel_launch(void* const* d_in, const int* in_sizes, int n_in,
                              void* d_out, int out_size, void* d_ws, size_t ws_size,
                              hipStream_t stream) {
    const float* x     = (const float*)d_in[0];
    const float* w_off = (const float*)d_in[1];
    const float* b_off = (const float*)d_in[2];
    const float* w_mod = (const float*)d_in[3];
    const float* b_mod = (const float*)d_in[4];
    const float* w     = (const float*)d_in[5];
    const float* bias  = (const float*)d_in[6];
    float* out = (float*)d_out;

    char* ws = (char*)d_ws;
    short* xt  = (short*)(ws);                   // 4,194,304 B
    short* wt2 = (short*)(ws + 4194304);         //    73,728 B
    short* wc2 = (short*)(ws + 4268032);         //    36,864 B

    hipLaunchKernelGGL(k_prep,      dim3(216),  dim3(256), 0, stream, w, w_off, w_mod, wt2, wc2);
    hipLaunchKernelGGL(k_transpose, dim3(512),  dim3(256), 0, stream, x, xt);
    hipLaunchKernelGGL(k_fused,     dim3(1024), dim3(128), 0, stream,
                       xt, wc2, wt2, b_off, b_mod, bias, out);
}

// Round 7
// 49.573 us; speedup vs baseline: 3.3118x; 1.1584x over previous
//
#include <hip/hip_runtime.h>
#include <math.h>

#define HW    64
#define NPIX  32768

typedef __attribute__((ext_vector_type(8))) short bf16x8;
typedef __attribute__((ext_vector_type(8))) short short8v;
typedef __attribute__((ext_vector_type(4))) float f32x4;

static __device__ inline short f2bf(float f) {
    union { float f; unsigned u; } v; v.f = f;
    unsigned r = v.u + 0x7fff + ((v.u >> 16) & 1);   // RNE
    return (short)(r >> 16);
}
static __device__ inline float bf2f(short s) {
    union { unsigned u; float f; } v; v.u = ((unsigned)(unsigned short)s) << 16;
    return v.f;
}

// ---------------------------------------------------------------------------
// Prep: wt2[f][o][c] bf16 (main weight), wc2[f][ch32][c] bf16 (off+mod, pad 32)
// ---------------------------------------------------------------------------
__global__ void k_prep(const float* __restrict__ w,
                       const float* __restrict__ w_off,
                       const float* __restrict__ w_mod,
                       short* __restrict__ wt2, short* __restrict__ wc2) {
    int t = blockIdx.x * 256 + threadIdx.x;
    if (t < 9 * 64 * 64) {
        int c = t & 63, o = (t >> 6) & 63, f = t >> 12;
        wt2[t] = f2bf(w[(o * 64 + c) * 9 + f]);
    }
    int u = t - 9 * 64 * 64;
    if (u >= 0 && u < 9 * 32 * 64) {
        int c = u & 63, ch = (u >> 6) & 31, f = u >> 11;
        float v = 0.f;
        if (ch < 18)      v = w_off[(ch * 64 + c) * 9 + f];
        else if (ch < 27) v = w_mod[((ch - 18) * 64 + c) * 9 + f];
        wc2[u] = f2bf(v);
    }
}

// ---------------------------------------------------------------------------
// Transpose x NCHW fp32 -> NHWC bf16 (xt[b][y][x][c]); block 256, grid B*H.
// ---------------------------------------------------------------------------
__global__ __launch_bounds__(256) void k_transpose(const float* __restrict__ x,
                                                   short* __restrict__ xt) {
    __shared__ float s[64 * 65];
    int tid = threadIdx.x;
    int by  = blockIdx.x;
    int b = by >> 6, y = by & 63;
    const float* xb = x + ((size_t)b * 64) * 4096 + y * 64;
    #pragma unroll
    for (int q = 0; q < 4; ++q) {
        int fi = q * 256 + tid;
        int c = fi >> 4, xq = (fi & 15) * 4;
        float4 v = *(const float4*)(xb + (size_t)c * 4096 + xq);
        s[c * 65 + xq + 0] = v.x; s[c * 65 + xq + 1] = v.y;
        s[c * 65 + xq + 2] = v.z; s[c * 65 + xq + 3] = v.w;
    }
    __syncthreads();
    short* dst = xt + ((size_t)(b * 64 + y)) * 4096;
    #pragma unroll
    for (int q = 0; q < 4; ++q) {
        int fi = q * 256 + tid;
        int xx = fi >> 4, c = (fi & 15) * 4;
        short4 v = make_short4(f2bf(s[(c + 0) * 65 + xx]), f2bf(s[(c + 1) * 65 + xx]),
                               f2bf(s[(c + 2) * 65 + xx]), f2bf(s[(c + 3) * 65 + xx]));
        *(short4*)(dst + xx * 64 + c) = v;
    }
}

// ---------------------------------------------------------------------------
// FUSED kernel, LDS-window version. Per half-row (b, i, jb), 256 thr / 4 waves:
//  ph1: stage 5x36-cell (rows i-2..i+2, cols jb-2..jb+33) bf16 window, swizzled
//  ph2: offset/mask conv MFMA from the window       (wave = (m-half, n-half))
//  ph3: bilinear meta -> LDS; corner encoded as swizzled LDS byte offset,
//       or sign-tagged global byte offset if outside the window (rare)
//       NOTE: strided loop — 288 entries > 256 threads (r6 bug: if(u<288)
//       left tap 8 uninitialized -> garbage LDS offsets -> aperture fault)
//  ph4: deformable gather FROM LDS + main MFMA out^T = W * S^T
//       (wave = (px-half, K-half)); exec-masked global fallback
//  ph5: cross-kk LDS reduce + coalesced store
// Grid 1024 -> 4 blocks/CU, 16 waves/CU; LDS 39936 B.
// ---------------------------------------------------------------------------
__global__ __launch_bounds__(256, 4) void k_fused(
        const short* __restrict__ xt,
        const short* __restrict__ wc2, const short* __restrict__ wt2,
        const float* __restrict__ b_off, const float* __restrict__ b_mod,
        const float* __restrict__ bias, float* __restrict__ out) {
    // [0,23040)        s_win : 180 cells x 128 B (bf16, XOR-swizzled chunks)
    // [23040,27648)    s_out : conv out [32ch][36px] f32          (ph2 -> ph3)
    // [27648,32256)    s_mW  : float4[288]                        (ph3 -> ph4)
    // [32256,36864)    s_mO  : int4[288]                          (ph3 -> ph4)
    // [23040,39936)    s_red : f32[2][64*33]                      (ph5, aliases)
    __shared__ __align__(16) char smem[39936];
    float*  s_out = (float*)(smem + 23040);
    float4* s_mW  = (float4*)(smem + 27648);
    int4*   s_mO  = (int4*)(smem + 32256);
    float*  s_red = (float*)(smem + 23040);

    int tid  = threadIdx.x;
    int lane = tid & 63;
    int wv   = __builtin_amdgcn_readfirstlane((int)(tid >> 6));
    int blk  = blockIdx.x;                     // (b*64+i)*2 + half
    int b = blk >> 7, i = (blk >> 1) & 63, jb = (blk & 1) * 32;
    const short* xb = xt + (size_t)b * 262144;

    int arow = lane & 15;
    int cg   = lane >> 4;
    int cgb  = cg * 8;

    // ---- phase 1: stage window (zero outside image), swizzled 16B chunks
    for (int u = tid; u < 1440; u += 256) {    // 180 cells x 8 chunks
        int cell = u >> 3, chunk = u & 7;
        int r = cell / 36, cc = cell - r * 36;
        int y = i - 2 + r, gx = jb - 2 + cc;
        short8v v = (short8v){0,0,0,0,0,0,0,0};
        if (((unsigned)y < 64u) & ((unsigned)gx < 64u))
            v = *(const short8v*)(xb + ((y << 6) + gx) * 64 + chunk * 8);
        *(short8v*)(smem + cell * 128 + ((chunk * 16) ^ ((cell & 7) << 4))) = v;
    }
    __syncthreads();

    // ---- phase 2: offset/mask conv. wave (mh = px-half, nh = ch-half).
    {
        int mh = wv & 1, nh = wv >> 1;
        f32x4 accc = (f32x4){0.f, 0.f, 0.f, 0.f};
        #pragma unroll
        for (int ky = 0; ky < 3; ++ky)
            #pragma unroll
            for (int kx = 0; kx < 3; ++kx) {
                int f = ky * 3 + kx;
                #pragma unroll
                for (int kk = 0; kk < 2; ++kk) {
                    bf16x8 bq = *(const bf16x8*)(wc2 + (f * 32 + nh * 16 + arow) * 64
                                                 + kk * 32 + cgb);
                    int cell = (ky + 1) * 36 + mh * 16 + arow + kx + 1;
                    const char* ap = smem + cell * 128
                                   + ((kk * 64 + cg * 16) ^ ((cell & 7) << 4));
                    accc = __builtin_amdgcn_mfma_f32_16x16x32_bf16(
                        *(const bf16x8*)ap, bq, accc, 0, 0, 0);
                }
            }
        __syncthreads();                       // window reads of ph2 done
        #pragma unroll
        for (int r = 0; r < 4; ++r)
            s_out[(nh * 16 + arow) * 36 + mh * 16 + cg * 4 + r] = accc[r];
    }
    __syncthreads();

    // ---- phase 3: bilinear meta (288 = 9 taps x 32 px) — STRIDED loop
    for (int u = tid; u < 288; u += 256) {
        int f = u >> 5, p = u & 31;
        float dy = s_out[(2 * f)     * 36 + p] + b_off[2 * f];
        float dx = s_out[(2 * f + 1) * 36 + p] + b_off[2 * f + 1];
        float mv = s_out[(18 + f)    * 36 + p] + b_mod[f];
        float m  = 1.f / (1.f + expf(-mv));

        float ys  = (float)(i - 1 + f / 3) + dy;
        float xs2 = (float)(jb + p - 1 + f % 3) + dx;
        float y0f = floorf(ys), x0f = floorf(xs2);
        int   y0  = (int)y0f,   x0  = (int)x0f;
        float fy = ys - y0f, fx = xs2 - x0f;

        bool vy0 = (unsigned)y0       < 64u, vy1 = (unsigned)(y0 + 1) < 64u;
        bool vx0 = (unsigned)x0       < 64u, vx1 = (unsigned)(x0 + 1) < 64u;
        float w00 = (vy0 & vx0) ? (1.f - fy) * (1.f - fx) * m : 0.f;
        float w01 = (vy0 & vx1) ? (1.f - fy) * fx         * m : 0.f;
        float w10 = (vy1 & vx0) ? fy         * (1.f - fx) * m : 0.f;
        float w11 = (vy1 & vx1) ? fy         * fx         * m : 0.f;

        int y0c = min(max(y0, 0), 63), y1c = min(max(y0 + 1, 0), 63);
        int x0c = min(max(x0, 0), 63), x1c = min(max(x0 + 1, 0), 63);

        // encode corner: in-window -> LDS cell byte base; else global byte | signbit
        #define ENCODE(yc, xc) ({                                          \
            int wr_ = (yc) - (i - 2), wc_ = (xc) - (jb - 2);               \
            bool inw_ = ((unsigned)wr_ < 5u) & ((unsigned)wc_ < 36u);      \
            int cell_ = wr_ * 36 + wc_;                                    \
            inw_ ? cell_ * 128                                             \
                 : (int)((((yc) * 64 + (xc)) * 128) | 0x80000000); })

        s_mW[u] = make_float4(w00, w01, w10, w11);
        s_mO[u] = make_int4(ENCODE(y0c, x0c), ENCODE(y0c, x1c),
                            ENCODE(y1c, x0c), ENCODE(y1c, x1c));
        #undef ENCODE
    }
    __syncthreads();

    // ---- phase 4: gather from LDS window + main MFMA. wave (ph, kk2).
    int ph  = wv & 1;
    int kk2 = wv >> 1;
    int kbyte = kk2 * 64 + cg * 16;            // byte offset of this lane's k-chunk
    f32x4 acc[4];
    #pragma unroll
    for (int mf = 0; mf < 4; ++mf) acc[mf] = (f32x4){0.f, 0.f, 0.f, 0.f};

    #pragma unroll
    for (int f = 0; f < 9; ++f) {
        int mi = f * 32 + ph * 16 + arow;
        float4 mW = s_mW[mi];
        int4   mO = s_mO[mi];
        bf16x8 c[4];
        int enc0 = mO.x, enc1 = mO.y, enc2 = mO.z, enc3 = mO.w;
        #define CORNER(idx, enc) {                                              \
            int cb = (enc) >= 0 ? (enc) : 0;                                    \
            c[idx] = *(const bf16x8*)(smem + cb + (kbyte ^ (((cb >> 7) & 7) << 4))); \
            if ((enc) < 0)                                                      \
                c[idx] = *(const bf16x8*)((const char*)xb                       \
                         + ((enc) & 0x7fffffff) + kbyte);                       \
        }
        CORNER(0, enc0) CORNER(1, enc1) CORNER(2, enc2) CORNER(3, enc3)
        #undef CORNER
        bf16x8 sf;
        #pragma unroll
        for (int j = 0; j < 8; ++j) {
            float s = mW.x * bf2f(c[0][j]) + mW.y * bf2f(c[1][j])
                    + mW.z * bf2f(c[2][j]) + mW.w * bf2f(c[3][j]);
            sf[j] = f2bf(s);
        }
        #pragma unroll
        for (int mf = 0; mf < 4; ++mf) {
            const short* wp = wt2 + (f * 64 + mf * 16 + arow) * 64 + kk2 * 32 + cgb;
            acc[mf] = __builtin_amdgcn_mfma_f32_16x16x32_bf16(
                *(const bf16x8*)wp, sf, acc[mf], 0, 0, 0);
        }
    }
    __syncthreads();                           // meta dead; s_red aliases

    // ---- phase 5: cross-kk reduce + store. acc: col=px(arow), row=o.
    #pragma unroll
    for (int mf = 0; mf < 4; ++mf)
        #pragma unroll
        for (int r = 0; r < 4; ++r)
            s_red[kk2 * 2112 + (mf * 16 + cg * 4 + r) * 33 + ph * 16 + arow] = acc[mf][r];
    __syncthreads();
    {
        int o  = tid >> 2;
        int pg = (tid & 3) * 8;
        float bv = bias[o];
        float* op = out + (((size_t)(b * 64 + o)) * 64 + i) * 64 + jb + pg;
        #pragma unroll
        for (int q = 0; q < 2; ++q) {
            float4 v;
            v.x = s_red[o * 33 + pg + q * 4 + 0] + s_red[2112 + o * 33 + pg + q * 4 + 0] + bv;
            v.y = s_red[o * 33 + pg + q * 4 + 1] + s_red[2112 + o * 33 + pg + q * 4 + 1] + bv;
            v.z = s_red[o * 33 + pg + q * 4 + 2] + s_red[2112 + o * 33 + pg + q * 4 + 2] + bv;
            v.w = s_red[o * 33 + pg + q * 4 + 3] + s_red[2112 + o * 33 + pg + q * 4 + 3] + bv;
            *(float4*)(op + q * 4) = v;
        }
    }
}

// ---------------------------------------------------------------------------
extern "C" void kernel_launch(void* const* d_in, const int* in_sizes, int n_in,
                              void* d_out, int out_size, void* d_ws, size_t ws_size,
                              hipStream_t stream) {
    const float* x     = (const float*)d_in[0];
    const float* w_off = (const float*)d_in[1];
    const float* b_off = (const float*)d_in[2];
    const float* w_mod = (const float*)d_in[3];
    const float* b_mod = (const float*)d_in[4];
    const float* w     = (const float*)d_in[5];
    const float* bias  = (const float*)d_in[6];
    float* out = (float*)d_out;

    char* ws = (char*)d_ws;
    short* xt  = (short*)(ws);                   // 4,194,304 B
    short* wt2 = (short*)(ws + 4194304);         //    73,728 B
    short* wc2 = (short*)(ws + 4268032);         //    36,864 B

    hipLaunchKernelGGL(k_prep,      dim3(216),  dim3(256), 0, stream, w, w_off, w_mod, wt2, wc2);
    hipLaunchKernelGGL(k_transpose, dim3(512),  dim3(256), 0, stream, x, xt);
    hipLaunchKernelGGL(k_fused,     dim3(1024), dim3(256), 0, stream,
                       xt, wc2, wt2, b_off, b_mod, bias, out);
}